// Round 5
// baseline (90.502 us; speedup 1.0000x reference)
//
#include <hip/hip_runtime.h>
#include <stdint.h>

#define T_LEN 512
#define I_LEN 5
#define CHUNK 8                    // timesteps per staged chunk
#define NCHUNK (T_LEN / CHUNK)     // 64

// ---- DPP helpers -----------------------------------------------------------
// Row rotate-right by N within each 16-lane row: lane i receives the value
// from lane (i - N) mod 16 (row-local). DPP_CTRL = 0x120 + N.
// mov_dpp has no 'old' operand -> single v_mov_b32_dpp, fusable into the
// consuming v_fmac_f32 by GCNDPPCombine (each result has exactly one use).
template<int N>
__device__ __forceinline__ float fror(float x) {
    return __int_as_float(__builtin_amdgcn_mov_dpp(
        __float_as_int(x), 0x120 + N, 0xF, 0xF, true));
}

// XOR-pattern DPP (verified rounds 1-4), used only in the final fc reduce.
//   0xB1 -> lane^1, 0x4E -> lane^2, 0x141 -> lane^7, 0x140 -> lane^15
template<int CTRL>
__device__ __forceinline__ float fdpp(float x) {
    return __int_as_float(__builtin_amdgcn_update_dpp(
        0, __float_as_int(x), CTRL, 0xF, 0xF, true));
}

// tanh with pre-scaled input: zs = 2*log2(e) * z  ->  tanh(z)
__device__ __forceinline__ float tanh_pre(float zs) {
    float e = __builtin_exp2f(zs);
    float r = __builtin_amdgcn_rcpf(e + 1.0f);
    return __builtin_fmaf(-2.0f, r, 1.0f);   // saturates to +/-1 correctly
}

// One global_load_lds_dwordx4: lane l loads 16B from its own global addr,
// writes LDS at (wave-uniform base) + lane*16.
__device__ __forceinline__ void gload_lds16(const float* g, float* l) {
    auto gp = reinterpret_cast<const __attribute__((address_space(1))) float*>(
        reinterpret_cast<uintptr_t>(g));
    auto lp = reinterpret_cast<__attribute__((address_space(3))) float*>(
        reinterpret_cast<uintptr_t>(l));
    __builtin_amdgcn_global_load_lds(gp, lp, 16, 0, 0);
}

// Volatile asm ds_read_b128: cannot be sunk or split by the scheduler.
#define DSR(dst, addr, OFFSTR)                                              \
    asm volatile("ds_read_b128 %0, %1 offset:" OFFSTR                      \
                 : "=v"(dst) : "v"(addr))

#define DSR10(q, addr)                                                      \
    do {                                                                    \
        DSR((q)[0], (addr), "0");   DSR((q)[1], (addr), "64");              \
        DSR((q)[2], (addr), "128"); DSR((q)[3], (addr), "192");             \
        DSR((q)[4], (addr), "256"); DSR((q)[5], (addr), "320");             \
        DSR((q)[6], (addr), "384"); DSR((q)[7], (addr), "448");             \
        DSR((q)[8], (addr), "512"); DSR((q)[9], (addr), "576");             \
    } while (0)

#define WAIT_LGKM0()                                                        \
    do {                                                                    \
        asm volatile("s_waitcnt lgkmcnt(0)" ::: "memory");                  \
        __builtin_amdgcn_sched_barrier(0);                                  \
    } while (0)

#define WAIT_VM(N)                                                          \
    asm volatile("s_waitcnt vmcnt(" #N ")" ::: "memory")

// Component extract with compile-time-constant idx (folds after unroll).
__device__ __forceinline__ float f4_at(const float4* b, int idx) {
    const float4 v = b[idx >> 2];
    switch (idx & 3) {
        case 0: return v.x;
        case 1: return v.y;
        case 2: return v.z;
        default: return v.w;
    }
}

// 8 timesteps from a 10-float4 (40-float) register block.
// whh[k] pairs with fror<k>(h): whh[k] = W_hh[j][(j+16-k)&15] (pre-scaled).
__device__ __forceinline__ void steps8(const float4* __restrict__ q, float& h,
                                       const float* __restrict__ wih,
                                       const float* __restrict__ whh,
                                       float bias) {
#pragma unroll
    for (int s = 0; s < 8; ++s) {
        const float x0 = f4_at(q, 5 * s + 0);
        const float x1 = f4_at(q, 5 * s + 1);
        const float x2 = f4_at(q, 5 * s + 2);
        const float x3 = f4_at(q, 5 * s + 3);
        const float x4 = f4_at(q, 5 * s + 4);

        // input projection (independent of h -> fills the write->DPP gap)
        float a0 = __builtin_fmaf(x0, wih[0], bias);
        float a1 = x1 * wih[1];
        a1 = __builtin_fmaf(x2, wih[2], a1);
        float a2 = x3 * wih[3];
        a2 = __builtin_fmaf(x4, wih[4], a2);
        float a3 = h * whh[0];                    // k=0: own h, no DPP

        // flat rotation gather: 15 single-hop DPP reads of h, one use each,
        // round-robin over 4 accumulator chains (dep distance 4 instrs).
        a0 = __builtin_fmaf(fror<1>(h),  whh[1],  a0);
        a1 = __builtin_fmaf(fror<2>(h),  whh[2],  a1);
        a2 = __builtin_fmaf(fror<3>(h),  whh[3],  a2);
        a3 = __builtin_fmaf(fror<4>(h),  whh[4],  a3);
        a0 = __builtin_fmaf(fror<5>(h),  whh[5],  a0);
        a1 = __builtin_fmaf(fror<6>(h),  whh[6],  a1);
        a2 = __builtin_fmaf(fror<7>(h),  whh[7],  a2);
        a3 = __builtin_fmaf(fror<8>(h),  whh[8],  a3);
        a0 = __builtin_fmaf(fror<9>(h),  whh[9],  a0);
        a1 = __builtin_fmaf(fror<10>(h), whh[10], a1);
        a2 = __builtin_fmaf(fror<11>(h), whh[11], a2);
        a3 = __builtin_fmaf(fror<12>(h), whh[12], a3);
        a0 = __builtin_fmaf(fror<13>(h), whh[13], a0);
        a1 = __builtin_fmaf(fror<14>(h), whh[14], a1);
        a2 = __builtin_fmaf(fror<15>(h), whh[15], a2);

        h = tanh_pre((a0 + a1) + (a2 + a3));
    }
}

__global__ __launch_bounds__(256, 2) void rnn_m2o_kernel(
    const float* __restrict__ x, const float* __restrict__ W_ih,
    const float* __restrict__ W_hh, const float* __restrict__ b_ih,
    const float* __restrict__ b_hh, const float* __restrict__ W_fc,
    const float* __restrict__ b_fc, float* __restrict__ out)
{
    const int tid  = threadIdx.x;
    const int wave = tid >> 6;        // 0..3
    const int lane = tid & 63;
    const int grp  = (tid >> 4) & 3;  // group-of-16 within wave
    const int j    = tid & 15;        // hidden unit owned by this lane
    const int b    = blockIdx.x * 16 + wave * 4 + grp;  // batch element

    // [wave][slot][256 dwords]: slot holds one chunk for 4 batches,
    // interleaved so (f4 i, batch b') sits at dword (4i+b')*4.
    __shared__ float lds_x[4][4][256];

    // Pre-scale all pre-activation weights by 2*log2(e): the accumulated z
    // arrives already multiplied for tanh_pre's exp2 (saves 1 mul/step).
    const float SC = 2.8853900817779268f;

    float wih[I_LEN];
#pragma unroll
    for (int i = 0; i < I_LEN; ++i) wih[i] = W_ih[j * I_LEN + i] * SC;
    const float bias = (b_ih[j] + b_hh[j]) * SC;

    // Rotation-matched W_hh row: whh[k] pairs with fror<k>(h) = h_{(j+16-k)&15}
    float whh[16];
#pragma unroll
    for (int k = 0; k < 16; ++k)
        whh[k] = W_hh[j * 16 + ((j + 16 - k) & 15)] * SC;

    const float wfc = W_fc[j];
    const float bfc = b_fc[0];

    // Staging source: lane l serves batch (l&3), float4 (l>>2).
    // Linear LDS write (lane*16B) lands (f4 i, batch b') at dword (4i+b')*4
    // -> group g's reads hit banks {4g..4g+3}: conflict-free (verified r4).
    const int f4i = lane >> 2;
    const int bat = lane & 3;
    const int lb  = blockIdx.x * 16 + wave * 4 + bat;
    const int ofl = (f4i < 10) ? f4i * 4 : 0;   // float offset within chunk
    const float* gsrc = x + (size_t)lb * (T_LEN * I_LEN) + ofl;

    const uint32_t lds_grp =
        (uint32_t)(uintptr_t)&lds_x[wave][0][0] + (uint32_t)(grp * 16);

    float4 qA[10], qB[10];
    float h = 0.0f;

    // Prologue: stage chunks 0..2, read chunk 0 into qA.
    gload_lds16(gsrc + 0 * (CHUNK * I_LEN), &lds_x[wave][0][0]);
    gload_lds16(gsrc + 1 * (CHUNK * I_LEN), &lds_x[wave][1][0]);
    gload_lds16(gsrc + 2 * (CHUNK * I_LEN), &lds_x[wave][2][0]);
    WAIT_VM(2);                       // chunk 0 landed
    DSR10(qA, lds_grp);               // slot 0
    WAIT_LGKM0();

    for (int n = 0; n < NCHUNK; n += 2) {
        // ---- even phase: compute chunk n (qA), prefetch-read chunk n+1 ----
        {
            const int cpf = (n + 3) & (NCHUNK - 1);
            gload_lds16(gsrc + cpf * (CHUNK * I_LEN),
                        &lds_x[wave][(n + 3) & 3][0]);
            WAIT_VM(2);               // chunk n+1 landed
            const uint32_t aB = lds_grp + (uint32_t)(((n + 1) & 3) * 1024);
            DSR10(qB, aB);
            steps8(qA, h, wih, whh, bias);
            WAIT_LGKM0();
        }
        // ---- odd phase: compute chunk n+1 (qB), prefetch-read chunk n+2 ---
        {
            const int cpf = (n + 4) & (NCHUNK - 1);
            gload_lds16(gsrc + cpf * (CHUNK * I_LEN),
                        &lds_x[wave][(n + 4) & 3][0]);
            WAIT_VM(2);               // chunk n+2 landed
            const uint32_t aA = lds_grp + (uint32_t)(((n + 2) & 3) * 1024);
            DSR10(qA, aA);
            steps8(qB, h, wih, whh, bias);
            WAIT_LGKM0();
        }
    }

    // fc + sigmoid: reduce h_j * wfc_j over the 16-lane group via DPP
    float r = h * wfc;
    r += fdpp<0xB1>(r);
    r += fdpp<0x4E>(r);
    r += fdpp<0x141>(r);
    r += fdpp<0x140>(r);
    if (j == 0) {
        float z = r + bfc;
        float sg = __builtin_amdgcn_rcpf(
            1.0f + __builtin_exp2f(z * -1.4426950408889634f));
        out[b] = sg;
    }
}

extern "C" void kernel_launch(void* const* d_in, const int* in_sizes, int n_in,
                              void* d_out, int out_size, void* d_ws, size_t ws_size,
                              hipStream_t stream) {
    const float* x    = (const float*)d_in[0];
    const float* W_ih = (const float*)d_in[1];
    const float* W_hh = (const float*)d_in[2];
    const float* b_ih = (const float*)d_in[3];
    const float* b_hh = (const float*)d_in[4];
    const float* W_fc = (const float*)d_in[5];
    const float* b_fc = (const float*)d_in[6];
    float* out = (float*)d_out;

    const int B = in_sizes[0] / (T_LEN * I_LEN);   // 8192
    const int blocks = B / 16;                     // 16 batch elements / block
    rnn_m2o_kernel<<<blocks, 256, 0, stream>>>(x, W_ih, W_hh, b_ih, b_hh,
                                               W_fc, b_fc, out);
}